// Round 4
// baseline (808.860 us; speedup 1.0000x reference)
//
#include <hip/hip_runtime.h>

typedef unsigned short u16;
typedef float f32x4 __attribute__((ext_vector_type(4)));
typedef unsigned int uint4v __attribute__((ext_vector_type(4)));

#define TT 2048
#define THEAD 2046
#define DD 1024
#define PP 512

#define LGKM0 asm volatile("s_waitcnt lgkmcnt(0)" ::: "memory")
#define SB0 __builtin_amdgcn_sched_barrier(0)
#define BAR __builtin_amdgcn_s_barrier()

// ---------- helpers ----------
__device__ __forceinline__ u16 f2bf(float f) {
  unsigned int u = __float_as_uint(f);
  return (u16)((u + 0x7fffu + ((u >> 16) & 1u)) >> 16);
}
__device__ __forceinline__ float bf2f(u16 h) {
  return __uint_as_float(((unsigned int)h) << 16);
}
__device__ __forceinline__ float tanh_fast(float x) {
  float cx = fminf(fmaxf(x, -15.f), 15.f);
  float e = __expf(2.f * cx);
  return (e - 1.f) * __builtin_amdgcn_rcpf(e + 1.f);
}
__device__ __forceinline__ void mfma16(f32x4& c, uint4v a, uint4v b) {
  asm("v_mfma_f32_16x16x32_bf16 %0, %1, %2, %0" : "+v"(c) : "v"(a), "v"(b));
}
// Ct swizzle: bijective per row; spreads both GEMM reads (2-way) and
// stage-D row reads (2-way; was 8-way without the (p>>6) term).
__device__ __forceinline__ int ct_idx(int r, int p) {
  return (r << 9) + (p ^ (((r & 7) ^ ((p >> 6) & 7)) << 3));
}
__device__ __forceinline__ uint4 cvt4(float4 v0, float4 v1) {
  uint4 pk;
  pk.x = (unsigned)f2bf(v0.x) | ((unsigned)f2bf(v0.y) << 16);
  pk.y = (unsigned)f2bf(v0.z) | ((unsigned)f2bf(v0.w) << 16);
  pk.z = (unsigned)f2bf(v1.x) | ((unsigned)f2bf(v1.y) << 16);
  pk.w = (unsigned)f2bf(v1.z) | ((unsigned)f2bf(v1.w) << 16);
  return pk;
}

// 16-MFMA cluster, A-frags from At (X tile), HALF selects k 0..31 / 32..63
#define AT_CLUSTER(HALF, BF)                                                   \
  {                                                                            \
    const int co_ = (((((HALF) << 2) + kg) ^ (lr & 7)) << 4);                  \
    uint4v a0_, a1_;                                                           \
    a0_ = *(const uint4v*)((const char*)At + ((0 + lr) << 7) + co_);           \
    a1_ = *(const uint4v*)((const char*)At + ((16 + lr) << 7) + co_);          \
    __builtin_amdgcn_s_setprio(1);                                             \
    mfma16(acc[0][0], a0_, BF[0]); mfma16(acc[0][1], a0_, BF[1]);              \
    mfma16(acc[0][2], a0_, BF[2]); mfma16(acc[0][3], a0_, BF[3]);              \
    mfma16(acc[1][0], a1_, BF[0]); mfma16(acc[1][1], a1_, BF[1]);              \
    mfma16(acc[1][2], a1_, BF[2]); mfma16(acc[1][3], a1_, BF[3]);              \
    a0_ = *(const uint4v*)((const char*)At + ((32 + lr) << 7) + co_);          \
    a1_ = *(const uint4v*)((const char*)At + ((48 + lr) << 7) + co_);          \
    mfma16(acc[2][0], a0_, BF[0]); mfma16(acc[2][1], a0_, BF[1]);              \
    mfma16(acc[2][2], a0_, BF[2]); mfma16(acc[2][3], a0_, BF[3]);              \
    mfma16(acc[3][0], a1_, BF[0]); mfma16(acc[3][1], a1_, BF[1]);              \
    mfma16(acc[3][2], a1_, BF[2]); mfma16(acc[3][3], a1_, BF[3]);              \
    __builtin_amdgcn_s_setprio(0);                                             \
  }

// 16-MFMA cluster, A-frags from Ct at K-step K (BK=32)
#define CT_CLUSTER(K, BF)                                                      \
  {                                                                            \
    const int p_ = ((K) << 5) + (kg << 3);                                     \
    const int e_ = p_ ^ (((lr & 7) ^ ((p_ >> 6) & 7)) << 3);                   \
    uint4v a0_, a1_;                                                           \
    a0_ = *(const uint4v*)&Ct[((0 + lr) << 9) + e_];                           \
    a1_ = *(const uint4v*)&Ct[((16 + lr) << 9) + e_];                          \
    __builtin_amdgcn_s_setprio(1);                                             \
    mfma16(acc[0][0], a0_, BF[0]); mfma16(acc[0][1], a0_, BF[1]);              \
    mfma16(acc[0][2], a0_, BF[2]); mfma16(acc[0][3], a0_, BF[3]);              \
    mfma16(acc[1][0], a1_, BF[0]); mfma16(acc[1][1], a1_, BF[1]);              \
    mfma16(acc[1][2], a1_, BF[2]); mfma16(acc[1][3], a1_, BF[3]);              \
    a0_ = *(const uint4v*)&Ct[((32 + lr) << 9) + e_];                          \
    a1_ = *(const uint4v*)&Ct[((48 + lr) << 9) + e_];                          \
    mfma16(acc[2][0], a0_, BF[0]); mfma16(acc[2][1], a0_, BF[1]);              \
    mfma16(acc[2][2], a0_, BF[2]); mfma16(acc[2][3], a0_, BF[3]);              \
    mfma16(acc[3][0], a1_, BF[0]); mfma16(acc[3][1], a1_, BF[1]);              \
    mfma16(acc[3][2], a1_, BF[2]); mfma16(acc[3][3], a1_, BF[3]);              \
    __builtin_amdgcn_s_setprio(0);                                             \
  }

// ---------- kernel 1: transpose+convert weights to bf16 ----------
__global__ __launch_bounds__(256) void cvt_k(const float* __restrict__ ph,
                                             const float* __restrict__ hw,
                                             u16* __restrict__ phT,
                                             u16* __restrict__ w0T,
                                             u16* __restrict__ w1T) {
  __shared__ float tl[32][33];
  const int bid = blockIdx.x, tid = threadIdx.x;
  const float* src;
  u16* dst;
  int SC, SR, r0, c0;
  if (bid < 512) {
    int tr = bid >> 4, tc = bid & 15;
    src = ph; SC = 512; dst = phT; SR = 1024; r0 = tr * 32; c0 = tc * 32;
  } else if (bid < 768) {
    int i = bid - 512; int tr = i >> 4, tc = i & 15;
    src = hw; SC = 512; dst = w0T; SR = 512; r0 = tr * 32; c0 = tc * 32;
  } else {
    int i = bid - 768; int tr = i >> 4, tc = i & 15;
    src = hw + 512 * 512; SC = 512; dst = w1T; SR = 512; r0 = tr * 32; c0 = tc * 32;
  }
  for (int i = tid; i < 1024; i += 256) {
    int r = i >> 5, c = i & 31;
    tl[r][c] = src[(size_t)(r0 + r) * SC + c0 + c];
  }
  __syncthreads();
  for (int i = tid; i < 1024; i += 256) {
    int r = i >> 5, c = i & 31;
    dst[(size_t)(c0 + r) * SR + r0 + c] = f2bf(tl[c][r]);
  }
}

// ---------- kernel 2: fp32 bias ----------
__global__ __launch_bounds__(256) void bias_k(const float* __restrict__ x,
                                              const float* __restrict__ pp,
                                              const float* __restrict__ pc,
                                              float* __restrict__ bias) {
  const int b = blockIdx.x >> 3, pt = blockIdx.x & 7, tid = threadIdx.x;
  __shared__ float sprep[DD], schild[DD];
  __shared__ float red[4][64];
  for (int i = tid; i < DD; i += 256) {
    sprep[i] = x[((size_t)b * TT + (TT - 2)) * DD + i];
    schild[i] = x[((size_t)b * TT + (TT - 1)) * DD + i];
  }
  __syncthreads();
  const int pl = tid & 63, kq = tid >> 6;
  const int p = pt * 64 + pl;
  float s = 0.f;
  for (int k = kq * 256; k < kq * 256 + 256; ++k)
    s += sprep[k] * pp[(size_t)k * PP + p] + schild[k] * pc[(size_t)k * PP + p];
  red[kq][pl] = s;
  __syncthreads();
  if (tid < 64)
    bias[(size_t)b * PP + pt * 64 + tid] =
        red[0][tid] + red[1][tid] + red[2][tid] + red[3][tid];
}

// ---------- kernel 3: fused main ----------
// 8 waves, wave = 64 rows x private 64-col strip. B-fragments load DIRECTLY
// global->VGPR (L2-resident weights, reg double-buffer, no LDS bounce).
// LDS = At (8KB X tile) + Ct (64KB) = 72KB -> 2 blocks/CU at VGPR<=128.
__global__ __launch_bounds__(512, 4) void fused_main(
    const float* __restrict__ x, const u16* __restrict__ phT,
    const u16* __restrict__ w0T, const u16* __restrict__ w1T,
    const float* __restrict__ bias, const float* __restrict__ scorer,
    const int* __restrict__ mask, float* __restrict__ out,
    float* __restrict__ partials) {
  __shared__ __align__(16) u16 At[64 * 64];
  __shared__ __align__(16) u16 Ct[64 * 512];

  const int tile = blockIdx.x, b = blockIdx.y;
  const int tid = threadIdx.x;
  const int lane = tid & 63, wid = tid >> 6;
  const int lr = lane & 15, kg = lane >> 4;
  const int r_st = tid >> 3, kp = tid & 7;

  const u16* __restrict__ phTw = phT + ((size_t)(wid << 6)) * DD;
  const u16* __restrict__ w0Tw = w0T + ((size_t)(wid << 6)) * PP;
  const u16* __restrict__ w1Tw = w1T + ((size_t)(wid << 6)) * PP;

  int boffA[4], boffH[4];
#pragma unroll
  for (int nr = 0; nr < 4; ++nr) {
    boffA[nr] = (((nr << 4) + lr) << 10) + (kg << 3);
    boffH[nr] = (((nr << 4) + lr) << 9) + (kg << 3);
  }

  const float* __restrict__ xbase =
      x + ((size_t)b * TT + tile * 64 + r_st) * DD + (kp << 3);
  u16* atdst = (u16*)((char*)At + (r_st << 7) + ((kp ^ (r_st & 7)) << 4));

  float bv[4];
#pragma unroll
  for (int nr = 0; nr < 4; ++nr)
    bv[nr] = bias[(b << 9) + (wid << 6) + (nr << 4) + lr];

  f32x4 acc[4][4];
#pragma unroll
  for (int mr = 0; mr < 4; ++mr)
#pragma unroll
    for (int nr = 0; nr < 4; ++nr) acc[mr][nr] = (f32x4){0.f, 0.f, 0.f, 0.f};

  uint4v bC[4], bN[4];
#pragma unroll
  for (int nr = 0; nr < 4; ++nr) bC[nr] = *(const uint4v*)(phTw + boffA[nr]);
  {  // X pair 0 -> At
    float4 v0 = *(const float4*)(xbase);
    float4 v1 = *(const float4*)(xbase + 4);
    uint4 pk = cvt4(v0, v1);
    *(uint4*)atdst = pk;
  }
  LGKM0;
  BAR; SB0;

  // ---- stage A: 16 pairs of BK=32 steps ----
#pragma unroll 1
  for (int p = 0; p < 15; ++p) {
    const u16* bkE = phTw + (p << 6);
#pragma unroll
    for (int nr = 0; nr < 4; ++nr)
      bN[nr] = *(const uint4v*)(bkE + 32 + boffA[nr]);
    float4 xv0 = *(const float4*)(xbase + ((p + 1) << 6));
    float4 xv1 = *(const float4*)(xbase + ((p + 1) << 6) + 4);
    AT_CLUSTER(0, bC);
#pragma unroll
    for (int nr = 0; nr < 4; ++nr)
      bC[nr] = *(const uint4v*)(bkE + 64 + boffA[nr]);
    uint4 pk = cvt4(xv0, xv1);
    AT_CLUSTER(1, bN);
    BAR;                     // all waves done reading At pair p
    *(uint4*)atdst = pk;     // write pair p+1
    LGKM0;
    BAR; SB0;
  }
  // peeled pair 15 (prefetches layer-0 step 0 into bC)
#pragma unroll
  for (int nr = 0; nr < 4; ++nr)
    bN[nr] = *(const uint4v*)(phTw + 992 + boffA[nr]);
  AT_CLUSTER(0, bC);
#pragma unroll
  for (int nr = 0; nr < 4; ++nr)
    bC[nr] = *(const uint4v*)(w0Tw + boffH[nr]);
  AT_CLUSTER(1, bN);

  // ---- epilogue A: bias + tanh -> Ct (wave-private cols; no pre-barrier) ----
#pragma unroll
  for (int mr = 0; mr < 4; ++mr)
#pragma unroll
    for (int nr = 0; nr < 4; ++nr) {
      const int c = (wid << 6) + (nr << 4) + lr;
#pragma unroll
      for (int j = 0; j < 4; ++j) {
        const int r = (mr << 4) + (kg << 2) + j;
        Ct[ct_idx(r, c)] = f2bf(tanh_fast(acc[mr][nr][j] + bv[nr]));
      }
      acc[mr][nr] = (f32x4){0.f, 0.f, 0.f, 0.f};
    }
  LGKM0;
  BAR; SB0;

  // ---- hidden layers: barrier-free K-loops ----
#pragma unroll 1
  for (int L = 0; L < 2; ++L) {
    const u16* __restrict__ wT = L ? w1Tw : w0Tw;
#pragma unroll 1
    for (int kk = 0; kk < 8; ++kk) {
      const int k = kk << 1;
#pragma unroll
      for (int nr = 0; nr < 4; ++nr)
        bN[nr] = *(const uint4v*)(wT + ((k + 1) << 5) + boffH[nr]);
      CT_CLUSTER(k, bC);
      if (kk < 7) {
#pragma unroll
        for (int nr = 0; nr < 4; ++nr)
          bC[nr] = *(const uint4v*)(wT + ((k + 2) << 5) + boffH[nr]);
      } else if (L == 0) {
#pragma unroll
        for (int nr = 0; nr < 4; ++nr)
          bC[nr] = *(const uint4v*)(w1Tw + boffH[nr]);
      }
      CT_CLUSTER(k + 1, bN);
    }
    BAR;  // all waves done reading Ct
#pragma unroll
    for (int mr = 0; mr < 4; ++mr)
#pragma unroll
      for (int nr = 0; nr < 4; ++nr) {
        const int c = (wid << 6) + (nr << 4) + lr;
#pragma unroll
        for (int j = 0; j < 4; ++j) {
          const int r = (mr << 4) + (kg << 2) + j;
          Ct[ct_idx(r, c)] = f2bf(tanh_fast(acc[mr][nr][j]));
        }
        acc[mr][nr] = (f32x4){0.f, 0.f, 0.f, 0.f};
      }
    LGKM0;
    BAR; SB0;
  }

  // ---- stage D: scores -> exp -> mask -> out, block partial sum ----
  {
    float* sredp = (float*)At;  // At dead; reuse for reduction
    const int r = tid >> 3, j = tid & 7;
    const int p0 = j << 6;
    float s = 0.f;
#pragma unroll
    for (int i = 0; i < 8; ++i) {
      uint4v v = *(const uint4v*)&Ct[ct_idx(r, p0 + (i << 3))];
      float4 sc0 = *(const float4*)(scorer + p0 + (i << 3));
      float4 sc1 = *(const float4*)(scorer + p0 + (i << 3) + 4);
      unsigned int u;
      u = v[0];
      s += bf2f((u16)(u & 0xffffu)) * sc0.x + bf2f((u16)(u >> 16)) * sc0.y;
      u = v[1];
      s += bf2f((u16)(u & 0xffffu)) * sc0.z + bf2f((u16)(u >> 16)) * sc0.w;
      u = v[2];
      s += bf2f((u16)(u & 0xffffu)) * sc1.x + bf2f((u16)(u >> 16)) * sc1.y;
      u = v[3];
      s += bf2f((u16)(u & 0xffffu)) * sc1.z + bf2f((u16)(u >> 16)) * sc1.w;
    }
    s += __shfl_down(s, 4, 8);
    s += __shfl_down(s, 2, 8);
    s += __shfl_down(s, 1, 8);
    if (j == 0) {
      const int tg = (tile << 6) + r;
      float e = 0.f;
      if (tg < THEAD && mask[(size_t)b * TT + tg] != 0) e = __expf(s);
      if (tg < THEAD) out[(size_t)b * THEAD + tg] = e;
      sredp[r] = e;
    }
    __syncthreads();
    if (tid < 64) {
      float v = sredp[tid];
      v += __shfl_down(v, 32);
      v += __shfl_down(v, 16);
      v += __shfl_down(v, 8);
      v += __shfl_down(v, 4);
      v += __shfl_down(v, 2);
      v += __shfl_down(v, 1);
      if (tid == 0) partials[(b << 5) + tile] = v;
    }
  }
}

// ---------- kernel 4: normalize ----------
__global__ __launch_bounds__(256) void norm_k(float* __restrict__ out,
                                              const float* __restrict__ partials) {
  const int b = blockIdx.y, j = blockIdx.x, tid = threadIdx.x;
  __shared__ float sinv;
  if (tid < 32) {
    float v = partials[(b << 5) + tid];
    v += __shfl_down(v, 16, 32);
    v += __shfl_down(v, 8, 32);
    v += __shfl_down(v, 4, 32);
    v += __shfl_down(v, 2, 32);
    v += __shfl_down(v, 1, 32);
    if (tid == 0) sinv = 1.f / (v + 1e-7f);
  }
  __syncthreads();
  const int t = (j << 8) + tid;
  if (t < THEAD) out[(size_t)b * THEAD + t] *= sinv;
}

extern "C" void kernel_launch(void* const* d_in, const int* in_sizes, int n_in,
                              void* d_out, int out_size, void* d_ws, size_t ws_size,
                              hipStream_t stream) {
  const float* x  = (const float*)d_in[0];
  const float* ph = (const float*)d_in[1];
  const float* pp = (const float*)d_in[2];
  const float* pc = (const float*)d_in[3];
  const float* hw = (const float*)d_in[4];
  const float* sc = (const float*)d_in[5];
  const int* mask = (const int*)d_in[6];
  float* out = (float*)d_out;

  char* ws = (char*)d_ws;
  u16* phT = (u16*)ws;
  u16* w0T = (u16*)(ws + (1 << 20));
  u16* w1T = (u16*)(ws + (1 << 20) + (1 << 19));
  float* biasb = (float*)(ws + (1 << 21));
  float* partials = (float*)(ws + (1 << 21) + 131072);

  cvt_k<<<1024, 256, 0, stream>>>(ph, hw, phT, w0T, w1T);
  bias_k<<<512, 256, 0, stream>>>(x, pp, pc, biasb);
  fused_main<<<dim3(32, 64), 512, 0, stream>>>(x, phT, w0T, w1T, biasb, sc,
                                               mask, out, partials);
  norm_k<<<dim3(8, 64), 256, 0, stream>>>(out, partials);
}

// Round 5
// 575.888 us; speedup vs baseline: 1.4045x; 1.4045x over previous
//
#include <hip/hip_runtime.h>

typedef unsigned short u16;
typedef float f32x4 __attribute__((ext_vector_type(4)));
typedef float fx4 __attribute__((ext_vector_type(4)));
typedef unsigned int uint4v __attribute__((ext_vector_type(4)));

#define TT 2048
#define THEAD 2046
#define DD 1024
#define PP 512

#define LGKM0 asm volatile("s_waitcnt lgkmcnt(0)" ::: "memory")
#define SB0 __builtin_amdgcn_sched_barrier(0)
#define BAR __builtin_amdgcn_s_barrier()
#define NTL(p) __builtin_nontemporal_load((const fx4*)(p))

// ---------- helpers ----------
__device__ __forceinline__ u16 f2bf(float f) {
  unsigned int u = __float_as_uint(f);
  return (u16)((u + 0x7fffu + ((u >> 16) & 1u)) >> 16);
}
__device__ __forceinline__ float bf2f(u16 h) {
  return __uint_as_float(((unsigned int)h) << 16);
}
__device__ __forceinline__ float tanh_fast(float x) {
  float cx = fminf(fmaxf(x, -15.f), 15.f);
  float e = __expf(2.f * cx);
  return (e - 1.f) * __builtin_amdgcn_rcpf(e + 1.f);
}
__device__ __forceinline__ void mfma16(f32x4& c, uint4v a, uint4v b) {
  asm("v_mfma_f32_16x16x32_bf16 %0, %1, %2, %0" : "+v"(c) : "v"(a), "v"(b));
}
// Ct swizzle: bijective; 2-way (free) for GEMM A-reads and stage-D reads.
__device__ __forceinline__ int ct_idx(int r, int p) {
  return (r << 9) + (p ^ (((r & 7) ^ ((p >> 6) & 7)) << 3));
}
__device__ __forceinline__ uint4 cvt4(fx4 v0, fx4 v1) {
  uint4 pk;
  pk.x = (unsigned)f2bf(v0[0]) | ((unsigned)f2bf(v0[1]) << 16);
  pk.y = (unsigned)f2bf(v0[2]) | ((unsigned)f2bf(v0[3]) << 16);
  pk.z = (unsigned)f2bf(v1[0]) | ((unsigned)f2bf(v1[1]) << 16);
  pk.w = (unsigned)f2bf(v1[2]) | ((unsigned)f2bf(v1[3]) << 16);
  return pk;
}
// Packed-weight element index: strip s=n>>7 (128-col wave strip), frag f,
// step t=k>>5. A wave's (t,f) load is 64 lanes x 16B, fully contiguous.
__device__ __forceinline__ int pk_idx(int n, int k, int K) {
  int s = n >> 7, f = (n >> 4) & 7, lr = n & 15;
  int t = k >> 5, kg = (k >> 3) & 3, ke = k & 7;
  return (((s * (K >> 5) + t) * 8 + f) << 9) + (kg << 7) + (lr << 3) + ke;
}

// load 8 B-frags (one BK=32 step) for this wave's strip, lane-contiguous
#define LOADB(DST, BASE, ST)                                                   \
  _Pragma("unroll") for (int f_ = 0; f_ < 8; ++f_)                             \
      DST[f_] = *(const uint4v*)((BASE) + ((((ST) << 3) + f_) << 9) + (lane << 3));

// 32-MFMA cluster, A from At (X tile), HALF = k 0..31 / 32..63 of window
#define AT_CLUSTER(HALF, BF)                                                   \
  {                                                                            \
    const int co_ = (((((HALF) << 2) + kg) ^ (lr & 7)) << 4);                  \
    uint4v a0_ = *(const uint4v*)((const char*)At + ((0 + lr) << 7) + co_);    \
    uint4v a1_ = *(const uint4v*)((const char*)At + ((16 + lr) << 7) + co_);   \
    uint4v a2_ = *(const uint4v*)((const char*)At + ((32 + lr) << 7) + co_);   \
    uint4v a3_ = *(const uint4v*)((const char*)At + ((48 + lr) << 7) + co_);   \
    __builtin_amdgcn_s_setprio(1);                                             \
    _Pragma("unroll") for (int nr_ = 0; nr_ < 8; ++nr_) {                      \
      mfma16(acc[0][nr_], a0_, BF[nr_]);                                       \
      mfma16(acc[1][nr_], a1_, BF[nr_]);                                       \
      mfma16(acc[2][nr_], a2_, BF[nr_]);                                       \
      mfma16(acc[3][nr_], a3_, BF[nr_]);                                       \
    }                                                                          \
    __builtin_amdgcn_s_setprio(0);                                             \
  }

// 32-MFMA cluster, A from Ct at BK=32 step ST
#define CT_CLUSTER(ST, BF)                                                     \
  {                                                                            \
    const int p_ = ((ST) << 5) + (kg << 3);                                    \
    const int e_ = p_ ^ (((lr & 7) ^ ((p_ >> 6) & 7)) << 3);                   \
    uint4v a0_ = *(const uint4v*)&Ct[((0 + lr) << 9) + e_];                    \
    uint4v a1_ = *(const uint4v*)&Ct[((16 + lr) << 9) + e_];                   \
    uint4v a2_ = *(const uint4v*)&Ct[((32 + lr) << 9) + e_];                   \
    uint4v a3_ = *(const uint4v*)&Ct[((48 + lr) << 9) + e_];                   \
    __builtin_amdgcn_s_setprio(1);                                             \
    _Pragma("unroll") for (int nr_ = 0; nr_ < 8; ++nr_) {                      \
      mfma16(acc[0][nr_], a0_, BF[nr_]);                                       \
      mfma16(acc[1][nr_], a1_, BF[nr_]);                                       \
      mfma16(acc[2][nr_], a2_, BF[nr_]);                                       \
      mfma16(acc[3][nr_], a3_, BF[nr_]);                                       \
    }                                                                          \
    __builtin_amdgcn_s_setprio(0);                                             \
  }

#define EPILOGUE(ADD)                                                          \
  _Pragma("unroll") for (int mr_ = 0; mr_ < 4; ++mr_)                          \
      _Pragma("unroll") for (int nr_ = 0; nr_ < 8; ++nr_) {                    \
    const int c_ = (wid << 7) + (nr_ << 4) + lr;                               \
    _Pragma("unroll") for (int j_ = 0; j_ < 4; ++j_) {                         \
      const int r_ = (mr_ << 4) + (kg << 2) + j_;                              \
      Ct[ct_idx(r_, c_)] = f2bf(tanh_fast(acc[mr_][nr_][j_] + (ADD)));         \
    }                                                                          \
    acc[mr_][nr_] = (f32x4){0.f, 0.f, 0.f, 0.f};                               \
  }

// ---------- kernel 1: convert weights to packed frag-order bf16 ----------
__global__ __launch_bounds__(256) void cvt_k(const float* __restrict__ ph,
                                             const float* __restrict__ hw,
                                             u16* __restrict__ phP,
                                             u16* __restrict__ w0P,
                                             u16* __restrict__ w1P) {
  const int z = blockIdx.z;
  if (z && blockIdx.y >= 16) return;
  const int K = z ? PP : DD;
  const float* __restrict__ src = (z == 0) ? ph : (z == 1 ? hw : hw + PP * PP);
  u16* __restrict__ dst = (z == 0) ? phP : (z == 1 ? w0P : w1P);
  const int l = threadIdx.x & 63, w = threadIdx.x >> 6;
  const int n = blockIdx.x * 64 + l;
  const int k0 = blockIdx.y * 32 + w * 8;
  float v[8];
#pragma unroll
  for (int j = 0; j < 8; ++j) v[j] = src[(size_t)(k0 + j) * PP + n];
  uint4 pk;
  pk.x = (unsigned)f2bf(v[0]) | ((unsigned)f2bf(v[1]) << 16);
  pk.y = (unsigned)f2bf(v[2]) | ((unsigned)f2bf(v[3]) << 16);
  pk.z = (unsigned)f2bf(v[4]) | ((unsigned)f2bf(v[5]) << 16);
  pk.w = (unsigned)f2bf(v[6]) | ((unsigned)f2bf(v[7]) << 16);
  *(uint4*)(dst + pk_idx(n, k0, K)) = pk;
}

// ---------- kernel 2: fp32 bias ----------
__global__ __launch_bounds__(256) void bias_k(const float* __restrict__ x,
                                              const float* __restrict__ pp,
                                              const float* __restrict__ pc,
                                              float* __restrict__ bias) {
  const int b = blockIdx.x >> 3, pt = blockIdx.x & 7, tid = threadIdx.x;
  __shared__ float sprep[DD], schild[DD];
  __shared__ float red[4][64];
  for (int i = tid; i < DD; i += 256) {
    sprep[i] = x[((size_t)b * TT + (TT - 2)) * DD + i];
    schild[i] = x[((size_t)b * TT + (TT - 1)) * DD + i];
  }
  __syncthreads();
  const int pl = tid & 63, kq = tid >> 6;
  const int p = pt * 64 + pl;
  float s = 0.f;
  for (int k = kq * 256; k < kq * 256 + 256; ++k)
    s += sprep[k] * pp[(size_t)k * PP + p] + schild[k] * pc[(size_t)k * PP + p];
  red[kq][pl] = s;
  __syncthreads();
  if (tid < 64)
    bias[(size_t)b * PP + pt * 64 + tid] =
        red[0][tid] + red[1][tid] + red[2][tid] + red[3][tid];
}

// ---------- kernel 3: fused main ----------
// 4 waves, wave = 64 rows x 128-col strip (acc 4x8 frags = 128 VGPR).
// B-frags: packed weights, direct global->VGPR, reg double-buffer.
// A-frags: LDS (At for stage A, Ct for hidden layers). 74 KB LDS, 2 blk/CU.
__global__ __launch_bounds__(256, 2) void fused_main(
    const float* __restrict__ x, const u16* __restrict__ phP,
    const u16* __restrict__ w0P, const u16* __restrict__ w1P,
    const float* __restrict__ bias, const float* __restrict__ scorer,
    const int* __restrict__ mask, float* __restrict__ out,
    float* __restrict__ partials) {
  __shared__ __align__(16) u16 At[64 * 64];   // 8 KB X window
  __shared__ __align__(16) u16 Ct[64 * 512];  // 64 KB composed tile
  __shared__ float ssc[PP];                   // 2 KB scorer

  const int tile = blockIdx.x, b = blockIdx.y;
  const int tid = threadIdx.x;
  const int lane = tid & 63, wid = tid >> 6;  // wave = n-strip (128 cols)
  const int lr = lane & 15, kg = lane >> 4;

  ssc[tid] = scorer[tid];
  ssc[tid + 256] = scorer[tid + 256];

  const u16* __restrict__ phW = phP + (wid << 17);  // strip base: 32*8*512
  const u16* __restrict__ w0W = w0P + (wid << 16);  // 16*8*512
  const u16* __restrict__ w1W = w1P + (wid << 16);

  f32x4 acc[4][8];
#pragma unroll
  for (int mr = 0; mr < 4; ++mr)
#pragma unroll
    for (int nr = 0; nr < 8; ++nr) acc[mr][nr] = (f32x4){0.f, 0.f, 0.f, 0.f};

  const int r_st = tid >> 2, q = tid & 3;
  const float* __restrict__ xb =
      x + ((size_t)b * TT + tile * 64 + r_st) * DD + (q << 4);
  char* atd = (char*)At + (r_st << 7);
  const int c0q = (((q << 1) ^ (r_st & 7)) << 4);
  const int c1q = ((((q << 1) + 1) ^ (r_st & 7)) << 4);

  uint4v bC[8], bN[8];
  // ---- prologue: B step0 + X window0 staged, X window1 prefetched ----
  LOADB(bC, phW, 0);
  fx4 xv0 = NTL(xb), xv1 = NTL(xb + 4), xv2 = NTL(xb + 8), xv3 = NTL(xb + 12);
  {
    uint4 pk0 = cvt4(xv0, xv1), pk1 = cvt4(xv2, xv3);
    *(uint4*)(atd + c0q) = pk0;
    *(uint4*)(atd + c1q) = pk1;
  }
  xv0 = NTL(xb + 64); xv1 = NTL(xb + 68);
  xv2 = NTL(xb + 72); xv3 = NTL(xb + 76);
  LGKM0; SB0;
  BAR;

  // ---- stage A: 16 windows x (2 BK=32 steps) ----
#pragma unroll 1
  for (int w = 0; w < 16; ++w) {
    LOADB(bN, phW, 2 * w + 1);
    AT_CLUSTER(0, bC);
    if (w < 15) { LOADB(bC, phW, 2 * w + 2); }
    else        { LOADB(bC, w0W, 0); }
    AT_CLUSTER(1, bN);
    if (w < 15) {
      uint4 pk0 = cvt4(xv0, xv1), pk1 = cvt4(xv2, xv3);
      BAR; SB0;  // all waves done reading window w
      *(uint4*)(atd + c0q) = pk0;
      *(uint4*)(atd + c1q) = pk1;
      LGKM0; SB0;
      BAR;       // window w+1 ready
      if (w < 14) {
        const float* xn = xb + ((w + 2) << 6);
        xv0 = NTL(xn); xv1 = NTL(xn + 4);
        xv2 = NTL(xn + 8); xv3 = NTL(xn + 12);
      }
    }
  }

  // ---- epilogue A: +bias, tanh -> Ct ----
  {
    float bv[8];
#pragma unroll
    for (int nr = 0; nr < 8; ++nr)
      bv[nr] = bias[(b << 9) + (wid << 7) + (nr << 4) + lr];
    EPILOGUE(bv[nr_]);
  }
  LGKM0; SB0;
  BAR;

  // ---- hidden layers: barrier-free K-loops (B wave-private in regs) ----
#pragma unroll 1
  for (int L = 0; L < 2; ++L) {
    const u16* __restrict__ wW = L ? w1W : w0W;
#pragma unroll 1
    for (int kk = 0; kk < 8; ++kk) {
      LOADB(bN, wW, 2 * kk + 1);
      CT_CLUSTER(2 * kk, bC);
      if (kk < 7)       { LOADB(bC, wW, 2 * kk + 2); }
      else if (L == 0)  { LOADB(bC, w1W, 0); }
      CT_CLUSTER(2 * kk + 1, bN);
    }
    BAR;  // all waves done reading Ct
    EPILOGUE(0.f);
    LGKM0; SB0;
    BAR;
  }

  // ---- stage D: scores -> exp -> mask -> out, block partial sum ----
  {
    float* sredp = (float*)At;  // At dead
    const int r = tid >> 2, j = tid & 3;
    const int p0 = j << 7;
    float s = 0.f;
#pragma unroll
    for (int i = 0; i < 16; ++i) {
      const int p = p0 + (i << 3);
      uint4v v = *(const uint4v*)&Ct[ct_idx(r, p)];
      fx4 s0 = *(const fx4*)&ssc[p];
      fx4 s1 = *(const fx4*)&ssc[p + 4];
      unsigned int u;
      u = v[0];
      s += bf2f((u16)(u & 0xffffu)) * s0[0] + bf2f((u16)(u >> 16)) * s0[1];
      u = v[1];
      s += bf2f((u16)(u & 0xffffu)) * s0[2] + bf2f((u16)(u >> 16)) * s0[3];
      u = v[2];
      s += bf2f((u16)(u & 0xffffu)) * s1[0] + bf2f((u16)(u >> 16)) * s1[1];
      u = v[3];
      s += bf2f((u16)(u & 0xffffu)) * s1[2] + bf2f((u16)(u >> 16)) * s1[3];
    }
    s += __shfl_down(s, 2, 4);
    s += __shfl_down(s, 1, 4);
    if (j == 0) {
      const int tg = (tile << 6) + r;
      float e = 0.f;
      if (tg < THEAD && mask[(size_t)b * TT + tg] != 0) e = __expf(s);
      if (tg < THEAD) out[(size_t)b * THEAD + tg] = e;
      sredp[r] = e;
    }
    __syncthreads();
    if (tid < 64) {
      float v = sredp[tid];
      v += __shfl_down(v, 32);
      v += __shfl_down(v, 16);
      v += __shfl_down(v, 8);
      v += __shfl_down(v, 4);
      v += __shfl_down(v, 2);
      v += __shfl_down(v, 1);
      if (tid == 0) partials[(b << 5) + tile] = v;
    }
  }
}

// ---------- kernel 4: normalize ----------
__global__ __launch_bounds__(256) void norm_k(float* __restrict__ out,
                                              const float* __restrict__ partials) {
  const int b = blockIdx.y, j = blockIdx.x, tid = threadIdx.x;
  __shared__ float sinv;
  if (tid < 32) {
    float v = partials[(b << 5) + tid];
    v += __shfl_down(v, 16, 32);
    v += __shfl_down(v, 8, 32);
    v += __shfl_down(v, 4, 32);
    v += __shfl_down(v, 2, 32);
    v += __shfl_down(v, 1, 32);
    if (tid == 0) sinv = 1.f / (v + 1e-7f);
  }
  __syncthreads();
  const int t = (j << 8) + tid;
  if (t < THEAD) out[(size_t)b * THEAD + t] *= sinv;
}

extern "C" void kernel_launch(void* const* d_in, const int* in_sizes, int n_in,
                              void* d_out, int out_size, void* d_ws, size_t ws_size,
                              hipStream_t stream) {
  const float* x  = (const float*)d_in[0];
  const float* ph = (const float*)d_in[1];
  const float* pp = (const float*)d_in[2];
  const float* pc = (const float*)d_in[3];
  const float* hw = (const float*)d_in[4];
  const float* sc = (const float*)d_in[5];
  const int* mask = (const int*)d_in[6];
  float* out = (float*)d_out;

  char* ws = (char*)d_ws;
  u16* phP = (u16*)ws;                               // 1 MiB
  u16* w0P = (u16*)(ws + (1 << 20));                 // 512 KiB
  u16* w1P = (u16*)(ws + (1 << 20) + (1 << 19));     // 512 KiB
  float* biasb = (float*)(ws + (1 << 21));           // 128 KiB
  float* partials = (float*)(ws + (1 << 21) + 131072);

  cvt_k<<<dim3(8, 32, 3), 256, 0, stream>>>(ph, hw, phP, w0P, w1P);
  bias_k<<<512, 256, 0, stream>>>(x, pp, pc, biasb);
  fused_main<<<dim3(32, 64), 256, 0, stream>>>(x, phP, w0P, w1P, biasb, sc,
                                               mask, out, partials);
  norm_k<<<dim3(8, 64), 256, 0, stream>>>(out, partials);
}

// Round 7
// 499.673 us; speedup vs baseline: 1.6188x; 1.1525x over previous
//
#include <hip/hip_runtime.h>

typedef unsigned short u16;
typedef float f32x4 __attribute__((ext_vector_type(4)));
typedef float fx4 __attribute__((ext_vector_type(4)));
typedef unsigned int uint4v __attribute__((ext_vector_type(4)));

#define TT 2048
#define THEAD 2046
#define DD 1024
#define PP 512

#define LGKM0 asm volatile("s_waitcnt lgkmcnt(0)" ::: "memory")
#define CFENCE asm volatile("" ::: "memory")
#define BAR __builtin_amdgcn_s_barrier()
#define NTL(p) __builtin_nontemporal_load((const fx4*)(p))

// ---------- helpers ----------
__device__ __forceinline__ u16 f2bf(float f) {
  unsigned int u = __float_as_uint(f);
  return (u16)((u + 0x7fffu + ((u >> 16) & 1u)) >> 16);
}
__device__ __forceinline__ float bf2f(u16 h) {
  return __uint_as_float(((unsigned int)h) << 16);
}
__device__ __forceinline__ float tanh_fast(float x) {
  float cx = fminf(fmaxf(x, -15.f), 15.f);
  float e = __expf(2.f * cx);
  return (e - 1.f) * __builtin_amdgcn_rcpf(e + 1.f);
}
__device__ __forceinline__ void mfma16(f32x4& c, uint4v a, uint4v b) {
  asm("v_mfma_f32_16x16x32_bf16 %0, %1, %2, %0" : "+v"(c) : "v"(a), "v"(b));
}
// Ct swizzle: bijective; 2-way (free) for GEMM A-reads and stage-D reads.
__device__ __forceinline__ int ct_idx(int r, int p) {
  return (r << 9) + (p ^ (((r & 7) ^ ((p >> 6) & 7)) << 3));
}
__device__ __forceinline__ uint4 cvt4(fx4 v0, fx4 v1) {
  uint4 pk;
  pk.x = (unsigned)f2bf(v0[0]) | ((unsigned)f2bf(v0[1]) << 16);
  pk.y = (unsigned)f2bf(v0[2]) | ((unsigned)f2bf(v0[3]) << 16);
  pk.z = (unsigned)f2bf(v1[0]) | ((unsigned)f2bf(v1[1]) << 16);
  pk.w = (unsigned)f2bf(v1[2]) | ((unsigned)f2bf(v1[3]) << 16);
  return pk;
}
// Packed-weight element index: strip s=n>>7 (128-col wave strip), frag f,
// step t=k>>5. A wave's (t,f) load is 64 lanes x 16B, fully contiguous.
__device__ __forceinline__ int pk_idx(int n, int k, int K) {
  int s = n >> 7, f = (n >> 4) & 7, lr = n & 15;
  int t = k >> 5, kg = (k >> 3) & 3, ke = k & 7;
  return (((s * (K >> 5) + t) * 8 + f) << 9) + (kg << 7) + (lr << 3) + ke;
}

// load 8 B-frags (one BK=32 step) for this wave's strip, lane-contiguous
#define LOADB(DST, BASE, ST)                                                   \
  _Pragma("unroll") for (int f_ = 0; f_ < 8; ++f_)                             \
      DST[f_] = *(const uint4v*)((BASE) + ((((ST) << 3) + f_) << 9) + (lane << 3));

// 32-MFMA cluster, A from X-window buffer BASE, HALF = k 0..31 / 32..63
#define AT_CLUSTER(BASE, HALF, BF)                                             \
  {                                                                            \
    const int co_ = (((((HALF) << 2) + kg) ^ (lr & 7)) << 4);                  \
    uint4v a0_ = *(const uint4v*)((const char*)(BASE) + ((0 + lr) << 7) + co_);\
    uint4v a1_ = *(const uint4v*)((const char*)(BASE) + ((16 + lr) << 7) + co_);\
    uint4v a2_ = *(const uint4v*)((const char*)(BASE) + ((32 + lr) << 7) + co_);\
    uint4v a3_ = *(const uint4v*)((const char*)(BASE) + ((48 + lr) << 7) + co_);\
    __builtin_amdgcn_s_setprio(1);                                             \
    _Pragma("unroll") for (int nr_ = 0; nr_ < 8; ++nr_) {                      \
      mfma16(acc[0][nr_], a0_, BF[nr_]);                                       \
      mfma16(acc[1][nr_], a1_, BF[nr_]);                                       \
      mfma16(acc[2][nr_], a2_, BF[nr_]);                                       \
      mfma16(acc[3][nr_], a3_, BF[nr_]);                                       \
    }                                                                          \
    __builtin_amdgcn_s_setprio(0);                                             \
  }

// 32-MFMA cluster, A from Ct at BK=32 step ST
#define CT_CLUSTER(ST, BF)                                                     \
  {                                                                            \
    const int p_ = ((ST) << 5) + (kg << 3);                                    \
    const int e_ = p_ ^ (((lr & 7) ^ ((p_ >> 6) & 7)) << 3);                   \
    uint4v a0_ = *(const uint4v*)&Ct[((0 + lr) << 9) + e_];                    \
    uint4v a1_ = *(const uint4v*)&Ct[((16 + lr) << 9) + e_];                   \
    uint4v a2_ = *(const uint4v*)&Ct[((32 + lr) << 9) + e_];                   \
    uint4v a3_ = *(const uint4v*)&Ct[((48 + lr) << 9) + e_];                   \
    __builtin_amdgcn_s_setprio(1);                                             \
    _Pragma("unroll") for (int nr_ = 0; nr_ < 8; ++nr_) {                      \
      mfma16(acc[0][nr_], a0_, BF[nr_]);                                       \
      mfma16(acc[1][nr_], a1_, BF[nr_]);                                       \
      mfma16(acc[2][nr_], a2_, BF[nr_]);                                       \
      mfma16(acc[3][nr_], a3_, BF[nr_]);                                       \
    }                                                                          \
    __builtin_amdgcn_s_setprio(0);                                             \
  }

#define EPILOGUE(ADD)                                                          \
  _Pragma("unroll") for (int mr_ = 0; mr_ < 4; ++mr_)                          \
      _Pragma("unroll") for (int nr_ = 0; nr_ < 8; ++nr_) {                    \
    const int c_ = (wid << 7) + (nr_ << 4) + lr;                               \
    _Pragma("unroll") for (int j_ = 0; j_ < 4; ++j_) {                         \
      const int r_ = (mr_ << 4) + (kg << 2) + j_;                              \
      Ct[ct_idx(r_, c_)] = f2bf(tanh_fast(acc[mr_][nr_][j_] + (ADD)));         \
    }                                                                          \
    acc[mr_][nr_] = (f32x4){0.f, 0.f, 0.f, 0.f};                               \
  }

// ---------- kernel 1: convert weights to packed frag-order bf16 ----------
__global__ __launch_bounds__(256) void cvt_k(const float* __restrict__ ph,
                                             const float* __restrict__ hw,
                                             u16* __restrict__ phP,
                                             u16* __restrict__ w0P,
                                             u16* __restrict__ w1P) {
  const int z = blockIdx.z;
  if (z && blockIdx.y >= 16) return;
  const int K = z ? PP : DD;
  const float* __restrict__ src = (z == 0) ? ph : (z == 1 ? hw : hw + PP * PP);
  u16* __restrict__ dst = (z == 0) ? phP : (z == 1 ? w0P : w1P);
  const int l = threadIdx.x & 63, w = threadIdx.x >> 6;
  const int n = blockIdx.x * 64 + l;
  const int k0 = blockIdx.y * 32 + w * 8;
  float v[8];
#pragma unroll
  for (int j = 0; j < 8; ++j) v[j] = src[(size_t)(k0 + j) * PP + n];
  uint4 pk;
  pk.x = (unsigned)f2bf(v[0]) | ((unsigned)f2bf(v[1]) << 16);
  pk.y = (unsigned)f2bf(v[2]) | ((unsigned)f2bf(v[3]) << 16);
  pk.z = (unsigned)f2bf(v[4]) | ((unsigned)f2bf(v[5]) << 16);
  pk.w = (unsigned)f2bf(v[6]) | ((unsigned)f2bf(v[7]) << 16);
  *(uint4*)(dst + pk_idx(n, k0, K)) = pk;
}

// ---------- kernel 2: fp32 bias ----------
__global__ __launch_bounds__(256) void bias_k(const float* __restrict__ x,
                                              const float* __restrict__ pp,
                                              const float* __restrict__ pc,
                                              float* __restrict__ bias) {
  const int b = blockIdx.x >> 3, pt = blockIdx.x & 7, tid = threadIdx.x;
  __shared__ float sprep[DD], schild[DD];
  __shared__ float red[4][64];
  for (int i = tid; i < DD; i += 256) {
    sprep[i] = x[((size_t)b * TT + (TT - 2)) * DD + i];
    schild[i] = x[((size_t)b * TT + (TT - 1)) * DD + i];
  }
  __syncthreads();
  const int pl = tid & 63, kq = tid >> 6;
  const int p = pt * 64 + pl;
  float s = 0.f;
  for (int k = kq * 256; k < kq * 256 + 256; ++k)
    s += sprep[k] * pp[(size_t)k * PP + p] + schild[k] * pc[(size_t)k * PP + p];
  red[kq][pl] = s;
  __syncthreads();
  if (tid < 64)
    bias[(size_t)b * PP + pt * 64 + tid] =
        red[0][tid] + red[1][tid] + red[2][tid] + red[3][tid];
}

// ---------- kernel 3: fused main ----------
// 4 waves, wave = 64 rows x 128-col strip (acc 4x8 frags = 128 VGPR).
// B-frags: packed weights, direct global->VGPR, reg double-buffer.
// X-window DOUBLE-buffered (one barrier per window, write targets other buf).
// Raw s_barrier is IntrNoMem at IR level -> every BAR is wrapped in
// asm-volatile "memory" fences (CFENCE) so LDS ops cannot drift across.
// LDS = 8+8+64 = 80 KB -> 2 blocks/CU. No min-occupancy launch_bounds
// (the 2nd arg halves the VGPR budget and spills: R4 496MB, R5 219MB writes).
__global__ __launch_bounds__(256) void fused_main(
    const float* __restrict__ x, const u16* __restrict__ phP,
    const u16* __restrict__ w0P, const u16* __restrict__ w1P,
    const float* __restrict__ bias, const float* __restrict__ scorer,
    const int* __restrict__ mask, float* __restrict__ out,
    float* __restrict__ partials) {
  __shared__ __align__(16) u16 At0[64 * 64];  // 8 KB X window (even)
  __shared__ __align__(16) u16 At1[64 * 64];  // 8 KB X window (odd)
  __shared__ __align__(16) u16 Ct[64 * 512];  // 64 KB composed tile

  const int tile = blockIdx.x, b = blockIdx.y;
  const int tid = threadIdx.x;
  const int lane = tid & 63, wid = tid >> 6;  // wave = n-strip (128 cols)
  const int lr = lane & 15, kg = lane >> 4;

  const u16* __restrict__ phW = phP + (wid << 17);  // strip base: 32*8*512
  const u16* __restrict__ w0W = w0P + (wid << 16);  // 16*8*512
  const u16* __restrict__ w1W = w1P + (wid << 16);

  f32x4 acc[4][8];
#pragma unroll
  for (int mr = 0; mr < 4; ++mr)
#pragma unroll
    for (int nr = 0; nr < 8; ++nr) acc[mr][nr] = (f32x4){0.f, 0.f, 0.f, 0.f};

  const int r_st = tid >> 2, q = tid & 3;
  const float* __restrict__ xb =
      x + ((size_t)b * TT + tile * 64 + r_st) * DD + (q << 4);
  char* atd0 = (char*)At0 + (r_st << 7);
  char* atd1 = (char*)At1 + (r_st << 7);
  const int c0q = (((q << 1) ^ (r_st & 7)) << 4);
  const int c1q = ((((q << 1) + 1) ^ (r_st & 7)) << 4);

  uint4v bC[8], bN[8];
  // ---- prologue: B step0; win0 -> buf0; pk=win1; xv=win2 in flight ----
  LOADB(bC, phW, 0);
  fx4 xv0 = NTL(xb), xv1 = NTL(xb + 4), xv2 = NTL(xb + 8), xv3 = NTL(xb + 12);
  {
    uint4 w0pk0 = cvt4(xv0, xv1), w0pk1 = cvt4(xv2, xv3);
    *(uint4*)(atd0 + c0q) = w0pk0;
    *(uint4*)(atd0 + c1q) = w0pk1;
  }
  xv0 = NTL(xb + 64); xv1 = NTL(xb + 68);
  xv2 = NTL(xb + 72); xv3 = NTL(xb + 76);
  uint4 pk0 = cvt4(xv0, xv1), pk1 = cvt4(xv2, xv3);  // win1
  xv0 = NTL(xb + 128); xv1 = NTL(xb + 132);
  xv2 = NTL(xb + 136); xv3 = NTL(xb + 140);          // win2
  LGKM0; CFENCE;
  BAR;
  CFENCE;

  // ---- stage A: 16 windows (K=64 each); reads buf[w&1], stores buf[~w&1] ----
#pragma unroll 2
  for (int w = 0; w < 16; ++w) {
    const u16* AtC = (w & 1) ? At1 : At0;
    char* atdN = (w & 1) ? atd0 : atd1;  // buf[(w+1)&1]
    if (w < 15) {                        // store win w+1 (other buffer: safe)
      *(uint4*)(atdN + c0q) = pk0;
      *(uint4*)(atdN + c1q) = pk1;
    }
    LOADB(bN, phW, 2 * w + 1);
    AT_CLUSTER(AtC, 0, bC);
    if (w < 15) { LOADB(bC, phW, 2 * w + 2); }
    else        { LOADB(bC, w0W, 0); }
    if (w < 14) { pk0 = cvt4(xv0, xv1); pk1 = cvt4(xv2, xv3); }  // win w+2
    if (w < 13) {
      const float* xn = xb + ((w + 3) << 6);
      xv0 = NTL(xn); xv1 = NTL(xn + 4);
      xv2 = NTL(xn + 8); xv3 = NTL(xn + 12);                     // win w+3
    }
    AT_CLUSTER(AtC, 1, bN);
    LGKM0; CFENCE;
    BAR;  // win w reads done by all waves; win w+1 store visible
    CFENCE;
  }

  // ---- epilogue A: +bias, tanh -> Ct (Ct not yet read by anyone) ----
  {
    float bv[8];
#pragma unroll
    for (int nr = 0; nr < 8; ++nr)
      bv[nr] = bias[(b << 9) + (wid << 7) + (nr << 4) + lr];
    EPILOGUE(bv[nr_]);
  }
  LGKM0; CFENCE;
  BAR;
  CFENCE;

  // ---- hidden layers: barrier-free K-loops (B wave-private in regs) ----
#pragma unroll 1
  for (int L = 0; L < 2; ++L) {
    const u16* __restrict__ wW = L ? w1W : w0W;
#pragma unroll 1
    for (int kk = 0; kk < 8; ++kk) {
      LOADB(bN, wW, 2 * kk + 1);
      CT_CLUSTER(2 * kk, bC);
      if (kk < 7)      { LOADB(bC, wW, 2 * kk + 2); }
      else if (L == 0) { LOADB(bC, w1W, 0); }
      CT_CLUSTER(2 * kk + 1, bN);
    }
    LGKM0; CFENCE;
    BAR;  // all waves done reading Ct
    CFENCE;
    EPILOGUE(0.f);
    LGKM0; CFENCE;
    BAR;  // new Ct visible
    CFENCE;
  }

  // ---- stage D: scores -> exp -> mask -> out, block partial sum ----
  {
    float* sredp = (float*)At0;  // At dead
    const int r = tid >> 2, j = tid & 3;
    const int p0 = j << 7;
    float s = 0.f;
#pragma unroll
    for (int i = 0; i < 16; ++i) {
      const int p = p0 + (i << 3);
      uint4v v = *(const uint4v*)&Ct[ct_idx(r, p)];
      fx4 s0 = *(const fx4*)(scorer + p);
      fx4 s1 = *(const fx4*)(scorer + p + 4);
      unsigned int u;
      u = v[0];
      s += bf2f((u16)(u & 0xffffu)) * s0[0] + bf2f((u16)(u >> 16)) * s0[1];
      u = v[1];
      s += bf2f((u16)(u & 0xffffu)) * s0[2] + bf2f((u16)(u >> 16)) * s0[3];
      u = v[2];
      s += bf2f((u16)(u & 0xffffu)) * s1[0] + bf2f((u16)(u >> 16)) * s1[1];
      u = v[3];
      s += bf2f((u16)(u & 0xffffu)) * s1[2] + bf2f((u16)(u >> 16)) * s1[3];
    }
    s += __shfl_down(s, 2, 4);
    s += __shfl_down(s, 1, 4);
    if (j == 0) {
      const int tg = (tile << 6) + r;
      float e = 0.f;
      if (tg < THEAD && mask[(size_t)b * TT + tg] != 0) e = __expf(s);
      if (tg < THEAD) out[(size_t)b * THEAD + tg] = e;
      sredp[r] = e;
    }
    __syncthreads();
    if (tid < 64) {
      float v = sredp[tid];
      v += __shfl_down(v, 32);
      v += __shfl_down(v, 16);
      v += __shfl_down(v, 8);
      v += __shfl_down(v, 4);
      v += __shfl_down(v, 2);
      v += __shfl_down(v, 1);
      if (tid == 0) partials[(b << 5) + tile] = v;
    }
  }
}

// ---------- kernel 4: normalize ----------
__global__ __launch_bounds__(256) void norm_k(float* __restrict__ out,
                                              const float* __restrict__ partials) {
  const int b = blockIdx.y, j = blockIdx.x, tid = threadIdx.x;
  __shared__ float sinv;
  if (tid < 32) {
    float v = partials[(b << 5) + tid];
    v += __shfl_down(v, 16, 32);
    v += __shfl_down(v, 8, 32);
    v += __shfl_down(v, 4, 32);
    v += __shfl_down(v, 2, 32);
    v += __shfl_down(v, 1, 32);
    if (tid == 0) sinv = 1.f / (v + 1e-7f);
  }
  __syncthreads();
  const int t = (j << 8) + tid;
  if (t < THEAD) out[(size_t)b * THEAD + t] *= sinv;
}

extern "C" void kernel_launch(void* const* d_in, const int* in_sizes, int n_in,
                              void* d_out, int out_size, void* d_ws, size_t ws_size,
                              hipStream_t stream) {
  const float* x  = (const float*)d_in[0];
  const float* ph = (const float*)d_in[1];
  const float* pp = (const float*)d_in[2];
  const float* pc = (const float*)d_in[3];
  const float* hw = (const float*)d_in[4];
  const float* sc = (const float*)d_in[5];
  const int* mask = (const int*)d_in[6];
  float* out = (float*)d_out;

  char* ws = (char*)d_ws;
  u16* phP = (u16*)ws;                               // 1 MiB
  u16* w0P = (u16*)(ws + (1 << 20));                 // 512 KiB
  u16* w1P = (u16*)(ws + (1 << 20) + (1 << 19));     // 512 KiB
  float* biasb = (float*)(ws + (1 << 21));           // 128 KiB
  float* partials = (float*)(ws + (1 << 21) + 131072);

  cvt_k<<<dim3(8, 32, 3), 256, 0, stream>>>(ph, hw, phP, w0P, w1P);
  bias_k<<<512, 256, 0, stream>>>(x, pp, pc, biasb);
  fused_main<<<dim3(32, 64), 256, 0, stream>>>(x, phP, w0P, w1P, biasb, sc,
                                               mask, out, partials);
  norm_k<<<dim3(8, 64), 256, 0, stream>>>(out, partials);
}